// Round 10
// baseline (101.726 us; speedup 1.0000x reference)
//
#include <hip/hip_runtime.h>
#include <hip/hip_bf16.h>

#define B_ 64
#define L_ 512
#define H_ 1024
#define EPS_ 1e-13f

typedef unsigned short u16;
typedef __attribute__((ext_vector_type(8))) short s16x8;
typedef __attribute__((ext_vector_type(4))) float f32x4;

__device__ __forceinline__ u16 f2bf(float f) {
  __hip_bfloat16 h = __float2bfloat16(f);
  union { __hip_bfloat16 h; u16 u; } c; c.h = h; return c.u;
}

// ---- Kernel 1: row softmax + mask renorm -> W bf16 (1x work, BW-bound). ----
__global__ __launch_bounds__(256) void softmax_rows(const float* __restrict__ att,
                                                    const float* __restrict__ mask,
                                                    u16* __restrict__ Wout) {
  const int w = threadIdx.x >> 6, lane = threadIdx.x & 63;
  const int row0 = blockIdx.x * 16 + w * 4;

  float a[4][8];
#pragma unroll
  for (int r = 0; r < 4; ++r) {
    const float* p = att + (size_t)(row0 + r) * L_ + lane * 8;
    float4 v0 = *(const float4*)p;
    float4 v1 = *(const float4*)(p + 4);
    a[r][0] = v0.x; a[r][1] = v0.y; a[r][2] = v0.z; a[r][3] = v0.w;
    a[r][4] = v1.x; a[r][5] = v1.y; a[r][6] = v1.z; a[r][7] = v1.w;
  }

  float m[4];
#pragma unroll
  for (int r = 0; r < 4; ++r) {
    m[r] = a[r][0];
#pragma unroll
    for (int j = 1; j < 8; ++j) m[r] = fmaxf(m[r], a[r][j]);
  }
#pragma unroll
  for (int off = 32; off > 0; off >>= 1)
#pragma unroll
    for (int r = 0; r < 4; ++r) m[r] = fmaxf(m[r], __shfl_xor(m[r], off));

  float z[4] = {0.f, 0.f, 0.f, 0.f};
#pragma unroll
  for (int r = 0; r < 4; ++r)
#pragma unroll
    for (int j = 0; j < 8; ++j) { a[r][j] = __expf(a[r][j] - m[r]); z[r] += a[r][j]; }
#pragma unroll
  for (int off = 32; off > 0; off >>= 1)
#pragma unroll
    for (int r = 0; r < 4; ++r) z[r] += __shfl_xor(z[r], off);

#pragma unroll
  for (int r = 0; r < 4; ++r) {
    const float mk = mask[row0 + r];
    const float c = (1.0f / z[r]) * (mk / (mk + EPS_));  // softmax row-sum == 1
    union { u16 u[8]; uint4 v; } wv;
#pragma unroll
    for (int j = 0; j < 8; ++j) wv.u[j] = f2bf(a[r][j] * c);
    *(uint4*)(Wout + (size_t)(row0 + r) * L_ + lane * 8) = wv.v;
  }
}

#define GLOAD(gp, lp)                                                              \
  __builtin_amdgcn_global_load_lds((const __attribute__((address_space(1))) unsigned*)(gp), \
                                   (__attribute__((address_space(3))) unsigned*)(void*)(lp), 16, 0, 0)

// ---- Kernel 2: GEMM out = W @ X (transpose folded into B staging).
// 256x256 tile, 8 waves. A: gload_lds ring-3. B: float2 reg-stage (8 VMEM/
// thread/tile, 3-iteration prefetch depth bx[3]) -> cvt bf16 -> [n][k] LDS
// ring-2. Steady counted vmcnt(18); setprio around MFMA; XCD-swizzled grid.
__global__ __launch_bounds__(512, 2) void gemm_xd(const u16* __restrict__ Wm,
                                                  const float* __restrict__ X,
                                                  float* __restrict__ out) {
  const int NT = 16;  // K=512 / BK=32
  const int swz = (blockIdx.x & 7) * 64 + (blockIdx.x >> 3);
  const int b  = swz >> 3;
  const int mt = (swz >> 2) & 1;  // M=512 -> 2 tiles of 256
  const int nt = swz & 3;         // N=1024 -> 4 tiles of 256

  __shared__ __align__(16) char lds[81920];  // A: 3x16KB @0; B: 2x16KB @49152

  const int t = threadIdx.x;
  const int lane = t & 63;
  const int w = t >> 6;               // 8 waves
  const int wm = w >> 2, wn = w & 3;  // 2x4 wave grid, 128x64 out each

  const u16* gW = Wm + ((size_t)b * L_ + mt * 256) * L_;  // L3-hot
  const float* gX = X + (size_t)b * L_ * H_ + nt * 256;

  // A staging via global_load_lds: rows r0 / r0+128, 16B slot t&3
  const int r0 = t >> 2;
  const int xsw = (r0 & 3) ^ ((r0 >> 2) & 3);
  const int scol = ((t & 3) ^ xsw) * 8;
  const u16* pA0 = gW + (size_t)r0 * L_ + scol;
  char* dA = lds + w * 1024;  // + region*16384 (+8192 for rows 128..255)

  // B staging: thread covers n0,n0+1 (float2 along n) x k-octet oq
  const int n0 = (t & 127) * 2;
  const int oq = t >> 7;  // 0..3 (k-octet within 32-k tile)
  const float* pX0 = gX + n0;
  // LDS write addresses for the two columns (slot = oq ^ ((n>>2)&3))
  const int wadr0 = 49152 + n0 * 64 + ((oq ^ ((n0 >> 2) & 3)) << 4);
  const int wadr1 = 49152 + (n0 + 1) * 64 + ((oq ^ (((n0 + 1) >> 2) & 3)) << 4);

  int offA[8], offB[4];
#pragma unroll
  for (int mf = 0; mf < 8; ++mf) {
    int r = wm * 128 + mf * 16 + (lane & 15);
    offA[mf] = r * 64 + ((((lane >> 4) ^ (r & 3) ^ ((r >> 2) & 3))) << 4);
  }
#pragma unroll
  for (int nf = 0; nf < 4; ++nf) {
    int r = wn * 64 + nf * 16 + (lane & 15);
    offB[nf] = 49152 + r * 64 + ((((lane >> 4) ^ ((r >> 2) & 3))) << 4);
  }

  f32x4 acc[8][4] = {};
  float2 bx[3][8];  // [tile%3][j] — compile-time indices only (full unroll)

#define A_ISSUE(tt)                                                       \
  do {                                                                    \
    GLOAD(pA0 + (tt) * 32, dA + ((tt) % 3) * 16384);                      \
    GLOAD(pA0 + (tt) * 32 + 128 * (size_t)L_, dA + ((tt) % 3) * 16384 + 8192); \
  } while (0)

#define B_ISSUE(tt)                                                       \
  do {                                                                    \
    _Pragma("unroll")                                                     \
    for (int j = 0; j < 8; ++j)                                           \
      bx[(tt) % 3][j] = *(const float2*)(pX0 + (size_t)((tt) * 32 + oq * 8 + j) * H_); \
  } while (0)

#define B_CVT_WRITE(tt)                                                   \
  do {                                                                    \
    union { u16 u[8]; uint4 v; } p0, p1;                                  \
    _Pragma("unroll")                                                     \
    for (int j = 0; j < 8; ++j) {                                         \
      p0.u[j] = f2bf(bx[(tt) % 3][j].x);                                  \
      p1.u[j] = f2bf(bx[(tt) % 3][j].y);                                  \
    }                                                                     \
    *(uint4*)(lds + ((tt) & 1) * 16384 + wadr0) = p0.v;                   \
    *(uint4*)(lds + ((tt) & 1) * 16384 + wadr1) = p1.v;                   \
  } while (0)

  // prologue: A0,B0,A1,B1,B2 in flight (FIFO: A0_2 B0_8 A1_2 B1_8 B2_8 = 28)
  A_ISSUE(0); B_ISSUE(0); A_ISSUE(1); B_ISSUE(1); B_ISSUE(2);
  asm volatile("s_waitcnt vmcnt(18)" ::: "memory");  // A0+B0 done
  B_CVT_WRITE(0);
  asm volatile("s_waitcnt lgkmcnt(0)" ::: "memory");
  __builtin_amdgcn_s_barrier();

#pragma unroll
  for (int k = 0; k < NT; ++k) {
    if (k + 2 < NT) A_ISSUE(k + 2);   // A first, then B (FIFO wait math)
    if (k + 3 < NT) B_ISSUE(k + 3);

    const char* baseA = lds + (k % 3) * 16384;
    const char* baseB = lds + (k & 1) * 16384;  // offB carries +49152
    s16x8 af[4], bf4[4];
#pragma unroll
    for (int nf = 0; nf < 4; ++nf) bf4[nf] = *(const s16x8*)(baseB + offB[nf]);
#pragma unroll
    for (int mf = 0; mf < 4; ++mf) af[mf] = *(const s16x8*)(baseA + offA[mf]);
    asm volatile("s_waitcnt lgkmcnt(0)" ::: "memory");

    __builtin_amdgcn_s_setprio(1);
#pragma unroll
    for (int mf = 0; mf < 4; ++mf)
#pragma unroll
      for (int nf = 0; nf < 4; ++nf)
        acc[mf][nf] = __builtin_amdgcn_mfma_f32_16x16x32_bf16(af[mf], bf4[nf], acc[mf][nf], 0, 0, 0);
    __builtin_amdgcn_s_setprio(0);

#pragma unroll
    for (int mf = 0; mf < 4; ++mf) af[mf] = *(const s16x8*)(baseA + offA[mf + 4]);
    asm volatile("s_waitcnt lgkmcnt(0)" ::: "memory");

    __builtin_amdgcn_s_setprio(1);
#pragma unroll
    for (int mf = 0; mf < 4; ++mf)
#pragma unroll
      for (int nf = 0; nf < 4; ++nf)
        acc[mf + 4][nf] = __builtin_amdgcn_mfma_f32_16x16x32_bf16(af[mf], bf4[nf], acc[mf + 4][nf], 0, 0, 0);
    __builtin_amdgcn_s_setprio(0);

    if (k + 1 < NT) {
      // retire tile k+1's A gload + B regloads (FIFO-exact counts)
      if (k <= 12)      asm volatile("s_waitcnt vmcnt(18)" ::: "memory");
      else if (k == 13) asm volatile("s_waitcnt vmcnt(10)" ::: "memory");
      else              asm volatile("s_waitcnt vmcnt(0)" ::: "memory");
      B_CVT_WRITE(k + 1);
      asm volatile("s_waitcnt lgkmcnt(0)" ::: "memory");
      __builtin_amdgcn_s_barrier();
    }
  }
#undef A_ISSUE
#undef B_ISSUE
#undef B_CVT_WRITE

  // epilogue: C/D layout col=lane&15, row=(lane>>4)*4+reg  [verified m89/m91]
  const int orow0 = mt * 256 + wm * 128 + ((lane >> 4) << 2);
  const int ocol0 = nt * 256 + wn * 64 + (lane & 15);
#pragma unroll
  for (int mf = 0; mf < 8; ++mf)
#pragma unroll
    for (int nf = 0; nf < 4; ++nf)
#pragma unroll
      for (int j = 0; j < 4; ++j) {
        int row = orow0 + mf * 16 + j;
        int col = ocol0 + nf * 16;
        out[((size_t)b * L_ + row) * H_ + col] = acc[mf][nf][j];
      }
}

extern "C" void kernel_launch(void* const* d_in, const int* in_sizes, int n_in,
                              void* d_out, int out_size, void* d_ws, size_t ws_size,
                              hipStream_t stream) {
  (void)in_sizes; (void)n_in; (void)out_size; (void)ws_size;
  const float* sent = (const float*)d_in[0];  // [B, L, H] f32
  const float* mask = (const float*)d_in[1];  // [B, L]    f32
  const float* att  = (const float*)d_in[2];  // [B, L, L] f32
  u16* Wm = (u16*)d_ws;                       // [B, L, L] bf16 (32 MiB)
  float* outp = (float*)d_out;                // [B, L, H] f32

  softmax_rows<<<2048, 256, 0, stream>>>(att, mask, Wm);
  gemm_xd<<<B_ * 2 * 4, 512, 0, stream>>>(Wm, sent, outp);
}

// Round 11
// 93.686 us; speedup vs baseline: 1.0858x; 1.0858x over previous
//
#include <hip/hip_runtime.h>
#include <hip/hip_bf16.h>

#define B_ 64
#define L_ 512
#define H_ 1024
#define EPS_ 1e-13f

typedef unsigned short u16;
typedef __attribute__((ext_vector_type(8))) short s16x8;
typedef __attribute__((ext_vector_type(4))) float f32x4;

__device__ __forceinline__ u16 f2bf(float f) {
  __hip_bfloat16 h = __float2bfloat16(f);
  union { __hip_bfloat16 h; u16 u; } c; c.h = h; return c.u;
}

// ---- Kernel 1: row softmax + mask renorm -> W bf16 (1x work, BW-bound). ----
__global__ __launch_bounds__(256) void softmax_rows(const float* __restrict__ att,
                                                    const float* __restrict__ mask,
                                                    u16* __restrict__ Wout) {
  const int w = threadIdx.x >> 6, lane = threadIdx.x & 63;
  const int row0 = blockIdx.x * 16 + w * 4;

  float a[4][8];
#pragma unroll
  for (int r = 0; r < 4; ++r) {
    const float* p = att + (size_t)(row0 + r) * L_ + lane * 8;
    float4 v0 = *(const float4*)p;
    float4 v1 = *(const float4*)(p + 4);
    a[r][0] = v0.x; a[r][1] = v0.y; a[r][2] = v0.z; a[r][3] = v0.w;
    a[r][4] = v1.x; a[r][5] = v1.y; a[r][6] = v1.z; a[r][7] = v1.w;
  }

  float m[4];
#pragma unroll
  for (int r = 0; r < 4; ++r) {
    m[r] = a[r][0];
#pragma unroll
    for (int j = 1; j < 8; ++j) m[r] = fmaxf(m[r], a[r][j]);
  }
#pragma unroll
  for (int off = 32; off > 0; off >>= 1)
#pragma unroll
    for (int r = 0; r < 4; ++r) m[r] = fmaxf(m[r], __shfl_xor(m[r], off));

  float z[4] = {0.f, 0.f, 0.f, 0.f};
#pragma unroll
  for (int r = 0; r < 4; ++r)
#pragma unroll
    for (int j = 0; j < 8; ++j) { a[r][j] = __expf(a[r][j] - m[r]); z[r] += a[r][j]; }
#pragma unroll
  for (int off = 32; off > 0; off >>= 1)
#pragma unroll
    for (int r = 0; r < 4; ++r) z[r] += __shfl_xor(z[r], off);

#pragma unroll
  for (int r = 0; r < 4; ++r) {
    const float mk = mask[row0 + r];
    const float c = (1.0f / z[r]) * (mk / (mk + EPS_));  // softmax row-sum == 1
    union { u16 u[8]; uint4 v; } wv;
#pragma unroll
    for (int j = 0; j < 8; ++j) wv.u[j] = f2bf(a[r][j] * c);
    *(uint4*)(Wout + (size_t)(row0 + r) * L_ + lane * 8) = wv.v;
  }
}

#define GLOAD(gp, lp)                                                              \
  __builtin_amdgcn_global_load_lds((const __attribute__((address_space(1))) unsigned*)(gp), \
                                   (__attribute__((address_space(3))) unsigned*)(void*)(lp), 16, 0, 0)

// ---- Kernel 2: GEMM out = W @ X. BOTH operands staged via global_load_lds
// with fully contiguous global reads. B (X tile) staged row-major f32 (each
// wave: one contiguous 1KB k-row per pass); transpose happens at LDS read
// time: per-fragment column gather (8x ds_read_b32, 2-way banks via
// octet-XOR source pre-swizzle) + cvt to bf16. A ring-3 x16KB, B ring-3
// x32KB = 144KB LDS, 1 block/CU, uniform depth-2 prefetch, vmcnt(6)/iter.
__global__ __launch_bounds__(512, 2) void gemm_xd(const u16* __restrict__ Wm,
                                                  const float* __restrict__ X,
                                                  float* __restrict__ out) {
  const int NT = 16;  // K=512 / BK=32
  const int swz = (blockIdx.x & 7) * 64 + (blockIdx.x >> 3);
  const int b  = swz >> 3;
  const int mt = (swz >> 2) & 1;  // M=512 -> 2 tiles of 256
  const int nt = swz & 3;         // N=1024 -> 4 tiles of 256

  __shared__ __align__(16) char lds[147456];  // A: 3x16KB @0; B(f32): 3x32KB @49152

  const int t = threadIdx.x;
  const int lane = t & 63;
  const int w = t >> 6;               // 8 waves
  const int wm = w >> 2, wn = w & 3;  // 2x4 wave grid, 128x64 out each

  const u16* gW = Wm + ((size_t)b * L_ + mt * 256) * L_;  // L3-hot (33 MB)
  const float* gX = X + (size_t)b * L_ * H_ + nt * 256;

  // ---- A staging (r5-proven): rows r0 / r0+128, 16B slot t&3, XOR swizzle ----
  const int r0 = t >> 2;
  const int xsw = (r0 & 3) ^ ((r0 >> 2) & 3);
  const int scol = ((t & 3) ^ xsw) * 8;
  const u16* pA0 = gW + (size_t)r0 * L_ + scol;
  char* dA = lds + w * 1024;  // + rgn*16384 (+8192 for rows 128..255)

  // ---- B staging: pass p (p=0..3) = k-octet p; wave w stages k-row p*8+w.
  // Source granule pre-swizzle lane^4 for odd octets (so column reads are
  // 2-way-bank-free); LDS row = contiguous 1KB.
  const float* pXw = gX + (size_t)w * H_;
  const int l4  = lane * 4;         // f32 offset of lane's 16B granule
  const int lx4 = (lane ^ 4) * 4;   // pre-swizzled granule for odd octets
  char* dBw = lds + 49152 + w * 1024;  // + rgn*32768 + p*8192

  int offA[8];
#pragma unroll
  for (int mf = 0; mf < 8; ++mf) {
    int r = wm * 128 + mf * 16 + (lane & 15);
    offA[mf] = r * 64 + ((((lane >> 4) ^ (r & 3) ^ ((r >> 2) & 3))) << 4);
  }
  // B column-gather byte offsets (within a B region): row = oct*8+j, col n
  // stored at element (n ^ ((oct&1)<<4)) of the 256-f32 row.
  int offBc[4];
#pragma unroll
  for (int nf = 0; nf < 4; ++nf) {
    int n = wn * 64 + nf * 16 + (lane & 15);
    int oct = lane >> 4;
    offBc[nf] = oct * 8192 + ((n ^ ((oct & 1) << 4)) << 2);
  }

  f32x4 acc[8][4] = {};

#define A_ISSUE(tt)                                                        \
  do {                                                                     \
    GLOAD(pA0 + (tt) * 32, dA + ((tt) % 3) * 16384);                       \
    GLOAD(pA0 + (tt) * 32 + 128 * (size_t)L_, dA + ((tt) % 3) * 16384 + 8192); \
  } while (0)

#define B_ISSUE(tt)                                                        \
  do {                                                                     \
    GLOAD(pXw + (size_t)((tt) * 32 + 0)  * H_ + l4,  dBw + ((tt) % 3) * 32768);         \
    GLOAD(pXw + (size_t)((tt) * 32 + 8)  * H_ + lx4, dBw + ((tt) % 3) * 32768 + 8192);  \
    GLOAD(pXw + (size_t)((tt) * 32 + 16) * H_ + l4,  dBw + ((tt) % 3) * 32768 + 16384); \
    GLOAD(pXw + (size_t)((tt) * 32 + 24) * H_ + lx4, dBw + ((tt) % 3) * 32768 + 24576); \
  } while (0)

  // prologue: tiles 0,1 in flight (6 vmem each)
  A_ISSUE(0); B_ISSUE(0); A_ISSUE(1); B_ISSUE(1);
  asm volatile("s_waitcnt vmcnt(6)" ::: "memory");  // tile 0 resident
  __builtin_amdgcn_s_barrier();

#pragma unroll
  for (int k = 0; k < NT; ++k) {
    if (k + 2 < NT) { A_ISSUE(k + 2); B_ISSUE(k + 2); }

    const char* baseA = lds + (k % 3) * 16384;
    const char* baseB = lds + 49152 + (k % 3) * 32768;

    s16x8 af[8];
#pragma unroll
    for (int mf = 0; mf < 8; ++mf) af[mf] = *(const s16x8*)(baseA + offA[mf]);

    s16x8 bf4[4];
#pragma unroll
    for (int nf = 0; nf < 4; ++nf) {
      union { u16 u[8]; s16x8 v; } pk;
#pragma unroll
      for (int j = 0; j < 8; ++j)
        pk.u[j] = f2bf(*(const float*)(baseB + offBc[nf] + j * 1024));
      bf4[nf] = pk.v;
    }
    asm volatile("s_waitcnt lgkmcnt(0)" ::: "memory");

    __builtin_amdgcn_s_setprio(1);
#pragma unroll
    for (int mf = 0; mf < 8; ++mf)
#pragma unroll
      for (int nf = 0; nf < 4; ++nf)
        acc[mf][nf] = __builtin_amdgcn_mfma_f32_16x16x32_bf16(af[mf], bf4[nf], acc[mf][nf], 0, 0, 0);
    __builtin_amdgcn_s_setprio(0);

    if (k + 1 < NT) {
      // retire tile k+1 (A 2 + B 4 = 6 ops), keep tile k+2's 6 in flight
      if (k + 2 < NT) asm volatile("s_waitcnt vmcnt(6)" ::: "memory");
      else            asm volatile("s_waitcnt vmcnt(0)" ::: "memory");
      __builtin_amdgcn_s_barrier();
    }
  }
#undef A_ISSUE
#undef B_ISSUE

  // epilogue: C/D layout col=lane&15, row=(lane>>4)*4+reg  [verified m89/m91]
  const int orow0 = mt * 256 + wm * 128 + ((lane >> 4) << 2);
  const int ocol0 = nt * 256 + wn * 64 + (lane & 15);
#pragma unroll
  for (int mf = 0; mf < 8; ++mf)
#pragma unroll
    for (int nf = 0; nf < 4; ++nf)
#pragma unroll
      for (int j = 0; j < 4; ++j) {
        int row = orow0 + mf * 16 + j;
        int col = ocol0 + nf * 16;
        out[((size_t)b * L_ + row) * H_ + col] = acc[mf][nf][j];
      }
}

extern "C" void kernel_launch(void* const* d_in, const int* in_sizes, int n_in,
                              void* d_out, int out_size, void* d_ws, size_t ws_size,
                              hipStream_t stream) {
  (void)in_sizes; (void)n_in; (void)out_size; (void)ws_size;
  const float* sent = (const float*)d_in[0];  // [B, L, H] f32
  const float* mask = (const float*)d_in[1];  // [B, L]    f32
  const float* att  = (const float*)d_in[2];  // [B, L, L] f32
  u16* Wm = (u16*)d_ws;                       // [B, L, L] bf16 (32 MiB)
  float* outp = (float*)d_out;                // [B, L, H] f32

  softmax_rows<<<2048, 256, 0, stream>>>(att, mask, Wm);
  gemm_xd<<<B_ * 2 * 4, 512, 0, stream>>>(Wm, sent, outp);
}